// Round 19
// baseline (293.395 us; speedup 1.0000x reference)
//
#include <hip/hip_runtime.h>
#include <hip/hip_bf16.h>

// FlowNetC correlation via bf16 MFMA Gram (16 tiles/parity).
// out[b, dyi*21+j, y, x] = (1/256) * sum_c in1[b,c,y,x] * in2[b,c,y2,x+2j-20], y2=y+2dyi-20.
// Parity split: x=2x'+p, u=2u'+p, u'=x'+j-10. Per (b,y,dyi,p):
//   G_p[x'][u'] = sum_c A_p[x'][c]*B_p[u'][c]  (64x64, K=256); j=u'-x'+10 in [0,21).
// Round-19 fix: L2-locality wg remap. r18 showed warm==cold dur at 12.9 TB/s operand
// reads (4.23 GB/dispatch) -> L3-BW-bound. New order per XCD: (b, y-parity, sub-band
// of 3 same-parity y, dyi, y) -- uses y2===y (mod 2): a 63-block run's read set =
// 3 A rows + 23 B rows ~= 3.4 MB < 4 MB L2, so reads stream from L2 (~34 TB/s) not L3.

typedef __attribute__((ext_vector_type(8))) short bf16x8;
typedef __attribute__((ext_vector_type(4))) float f32x4;
typedef __attribute__((ext_vector_type(4))) unsigned u32x4;

constexpr int Bn = 8, Cn = 256, Hn = 96, Wn = 128, GW = 21;
constexpr int KC = 32, NCH = Cn / KC;     // 8 chunks of 32 channels
constexpr int NWG = Bn * Hn * GW;         // 16128, divisible by 8
constexpr int JW = 23;                    // sout pad: scatter ~2-way, transpose-read free

__device__ inline unsigned pack_bf16(float lo, float hi) {
    __hip_bfloat16 l = __float2bfloat16(lo);
    __hip_bfloat16 h = __float2bfloat16(hi);
    unsigned short lu, hu;
    __builtin_memcpy(&lu, &l, 2);
    __builtin_memcpy(&hu, &h, 2);
    return (unsigned)lu | ((unsigned)hu << 16);
}

// LDS-visibility barrier WITHOUT the vmcnt(0) drain of __syncthreads() (rule #18).
__device__ inline void lds_barrier() {
    asm volatile("s_waitcnt lgkmcnt(0)" ::: "memory");
    __builtin_amdgcn_s_barrier();
    __builtin_amdgcn_sched_barrier(0);
}

__global__ __launch_bounds__(256) void corr_mfma(
    const float* __restrict__ in1, const float* __restrict__ in2,
    float* __restrict__ out)
{
    // [dbuf][panel: Ae,Ao,Be,Bo][1024 uints]; panel = [mt4][kg4][pos16][ku4] of bf16x2
    // Epilogue overlays sout[128][JW] floats (2944 <= 8192 dwords).
    __shared__ unsigned lds[2][4][1024];

    // ---- L2-locality decode: XCD owns y-band of 12; within: (b, par, sub, dyi, yw)
    int orig = blockIdx.x;
    int xcd  = orig & 7;
    int i    = orig >> 3;            // 0..2015
    int yw   = i % 3;  int t = i / 3;
    int dyi  = t % 21; t /= 21;      // t in [0,32)
    int sub  = t & 1;
    int par  = (t >> 1) & 1;
    int b    = t >> 2;               // 0..7
    int y    = 12 * xcd + par + 2 * (3 * sub + yw);   // bijective: yy in [0,12)

    int y2  = y + 2 * dyi - 20;
    bool y2ok = (y2 >= 0) && (y2 < Hn);

    int tid = threadIdx.x;
    int w   = tid >> 6;          // wave 0..3
    int l   = tid & 63;
    int p   = w >> 1;            // parity
    int h   = w & 1;             // x-half: mt in {2h, 2h+1}
    int g   = l >> 4;            // k-group
    int m16 = l & 15;

    const size_t chw = (size_t)Hn * Wn;
    const float* pA = in1 + ((size_t)b * Cn) * chw + (size_t)y * Wn;
    const float* pB = in2 + ((size_t)b * Cn) * chw + (size_t)(y2ok ? y2 : 0) * Wn;

    // staging task: thread = (tm = x-pair 0..63, tg = kg 0..3); owns channels 8tg..8tg+7
    int tm = tid & 63;
    int tg = tid >> 6;
    const int loff = ((tm >> 4) * 4 + tg) * 64 + (tm & 15) * 4;   // b128-aligned

    f32x4 acc[2][4] = {};        // acc[a][n] = tile (mt=2h+a, nt=n)

    // raw load values as scalar floats (two prefetch sets)
    float ax0[8], ay0[8], bx0[8], by0[8];
    float ax1[8], ay1[8], bx1[8], by1[8];

    auto prefetch = [&](int chunk, float (&ax)[8], float (&ay)[8],
                        float (&bx)[8], float (&by)[8]) {
        size_t base = (size_t)(chunk * KC + 8 * tg) * chw + 2 * tm;
#pragma unroll
        for (int k = 0; k < 8; ++k) {
            float2 tA = *(const float2*)(pA + base + (size_t)k * chw);
            float2 tB = *(const float2*)(pB + base + (size_t)k * chw);
            ax[k] = tA.x; ay[k] = tA.y;
            bx[k] = tB.x; by[k] = tB.y;
        }
        __builtin_amdgcn_sched_barrier(0);   // pin issue point: loads go out here
    };

    auto writeout = [&](int buf, float (&ax)[8], float (&ay)[8],
                        float (&bx)[8], float (&by)[8]) {
#pragma unroll
        for (int k = 0; k < 8; ++k)
            asm volatile("" : "+v"(ax[k]), "+v"(ay[k]), "+v"(bx[k]), "+v"(by[k]));
        u32x4 ae, ao, be, bo;
#pragma unroll
        for (int ku = 0; ku < 4; ++ku) {
            ae[ku] = pack_bf16(ax[2 * ku], ax[2 * ku + 1]);
            ao[ku] = pack_bf16(ay[2 * ku], ay[2 * ku + 1]);
            be[ku] = pack_bf16(bx[2 * ku], bx[2 * ku + 1]);
            bo[ku] = pack_bf16(by[2 * ku], by[2 * ku + 1]);
        }
        *(u32x4*)&lds[buf][0][loff] = ae;
        *(u32x4*)&lds[buf][1][loff] = ao;
        *(u32x4*)&lds[buf][2][loff] = be;
        *(u32x4*)&lds[buf][3][loff] = bo;
    };

    auto compute = [&](int buf) {
        const unsigned* Pa = &lds[buf][p][0];
        const unsigned* Pb = &lds[buf][2 + p][0];
        int fo = g * 64 + m16 * 4;
        bf16x8 A0  = *(const bf16x8*)(Pa + (2 * h + 0) * 256 + fo);
        bf16x8 A1  = *(const bf16x8*)(Pa + (2 * h + 1) * 256 + fo);
        bf16x8 Bf0 = *(const bf16x8*)(Pb + 0 * 256 + fo);
        bf16x8 Bf1 = *(const bf16x8*)(Pb + 1 * 256 + fo);
        bf16x8 Bf2 = *(const bf16x8*)(Pb + 2 * 256 + fo);
        bf16x8 Bf3 = *(const bf16x8*)(Pb + 3 * 256 + fo);
        acc[0][0] = __builtin_amdgcn_mfma_f32_16x16x32_bf16(A0, Bf0, acc[0][0], 0, 0, 0);
        acc[0][1] = __builtin_amdgcn_mfma_f32_16x16x32_bf16(A0, Bf1, acc[0][1], 0, 0, 0);
        acc[0][2] = __builtin_amdgcn_mfma_f32_16x16x32_bf16(A0, Bf2, acc[0][2], 0, 0, 0);
        acc[0][3] = __builtin_amdgcn_mfma_f32_16x16x32_bf16(A0, Bf3, acc[0][3], 0, 0, 0);
        acc[1][0] = __builtin_amdgcn_mfma_f32_16x16x32_bf16(A1, Bf0, acc[1][0], 0, 0, 0);
        acc[1][1] = __builtin_amdgcn_mfma_f32_16x16x32_bf16(A1, Bf1, acc[1][1], 0, 0, 0);
        acc[1][2] = __builtin_amdgcn_mfma_f32_16x16x32_bf16(A1, Bf2, acc[1][2], 0, 0, 0);
        acc[1][3] = __builtin_amdgcn_mfma_f32_16x16x32_bf16(A1, Bf3, acc[1][3], 0, 0, 0);
    };

    if (y2ok) {
        prefetch(0, ax0, ay0, bx0, by0);
        prefetch(1, ax1, ay1, bx1, by1);
        for (int it = 0; it < NCH; it += 2) {
            writeout(0, ax0, ay0, bx0, by0);
            lds_barrier();
            if (it + 2 < NCH) prefetch(it + 2, ax0, ay0, bx0, by0);
            compute(0);
            writeout(1, ax1, ay1, bx1, by1);
            lds_barrier();
            if (it + 3 < NCH) prefetch(it + 3, ax1, ay1, bx1, by1);
            compute(1);
        }
    }

    // ---- epilogue: LDS-transposed, coalesced stores ----
    __syncthreads();                       // all compute/LDS reads done; reuse LDS
    float* sout = (float*)&lds[0][0][0];   // sout[x][JW], x in [0,128), j in [0,21)

    for (int i2 = tid; i2 < Wn * JW; i2 += 256) sout[i2] = 0.0f;
    __syncthreads();                       // zeros visible

    if (y2ok) {
        const float scale = 1.0f / 256.0f;
#pragma unroll
        for (int a = 0; a < 2; ++a)
#pragma unroll
            for (int n = 0; n < 4; ++n)
#pragma unroll
                for (int r = 0; r < 4; ++r) {
                    int xp = (2 * h + a) * 16 + g * 4 + r;   // x' (C/D row)
                    int up = n * 16 + m16;                   // u' (C/D col)
                    int j  = up - xp + 10;
                    if ((unsigned)j < 21u)
                        sout[(2 * xp + p) * JW + j] = acc[a][n][r] * scale;
                }
    }
    __syncthreads();                       // scatter visible

    unsigned base0 = (unsigned)(((b * (GW * GW) + dyi * GW) * Hn + y) * Wn);
    constexpr unsigned PLANE = (unsigned)(Hn * Wn);
    for (int s = tid; s < GW * Wn; s += 256) {
        int j = s >> 7;                    // s / 128
        int x = s & 127;
        out[base0 + (unsigned)j * PLANE + (unsigned)x] = sout[x * JW + j];
    }
}

extern "C" void kernel_launch(void* const* d_in, const int* in_sizes, int n_in,
                              void* d_out, int out_size, void* d_ws, size_t ws_size,
                              hipStream_t stream) {
    const float* in1 = (const float*)d_in[0];
    const float* in2 = (const float*)d_in[1];
    float* out = (float*)d_out;
    corr_mfma<<<NWG, 256, 0, stream>>>(in1, in2, out);
}